// Round 1
// baseline (772.851 us; speedup 1.0000x reference)
//
#include <hip/hip_runtime.h>
#include <hip/hip_bf16.h>

#define M_SAMPLES 524288
#define NRAYS 8192
#define GXD 160
#define GYD 160
#define GZD 128
#define GYZ (GYD*GZD)
#define ACT_SHIFT -13.81550955796f
#define LDSROW 136

typedef __bf16 bf16x8 __attribute__((ext_vector_type(8)));
typedef float f32x4 __attribute__((ext_vector_type(4)));

static __device__ inline unsigned short f2bf(float f){
  __hip_bfloat16 h = __float2bfloat16(f);
  unsigned short u; __builtin_memcpy(&u, &h, 2); return u;
}
static __device__ inline float bf2f(unsigned short u){
  return __uint_as_float(((unsigned)u) << 16);
}

// ---------------- mask dtype detection (numpy bool bytes vs int32) -------------
__global__ void k_detect(const unsigned int* __restrict__ mw, int* __restrict__ flag){
  if(threadIdx.x == 0){
    int f = 0;
    for(int i = 0; i < 64; ++i) if(mw[i] > 1u) f = 1;   // byte-packed bools -> words like 0x01010101
    *flag = f;                                          // 1 = byte format, 0 = int32 format
  }
}

// ---------------- weight transpose + bf16 convert ------------------------------
// wt0: [128][96] (k>=75 zero-padded), wt1/wt2: [128][128], layout [n][k]
__global__ __launch_bounds__(256) void k_prep_w(const float* __restrict__ W0,
    const float* __restrict__ W1, const float* __restrict__ W2,
    unsigned short* __restrict__ wt0, unsigned short* __restrict__ wt1,
    unsigned short* __restrict__ wt2)
{
  int t = blockIdx.x*256 + threadIdx.x;
  if(t < 128*96){
    int n = t/96, k = t%96;
    float v = (k < 75) ? W0[k*128 + n] : 0.f;
    wt0[t] = f2bf(v);
  } else if(t < 128*96 + 16384){
    int j = t - 128*96; int n = j/128, k = j%128;
    wt1[j] = f2bf(W1[k*128 + n]);
  } else if(t < 128*96 + 32768){
    int j = t - 128*96 - 16384; int n = j/128, k = j%128;
    wt2[j] = f2bf(W2[k*128 + n]);
  }
}

// ---------------- per-ray view-dir positional embedding ------------------------
// layout: [v(3), sin(3*4), cos(3*4)] = 27, sin block index = coord*4 + pe
__global__ __launch_bounds__(256) void k_viewemb(const float* __restrict__ vd,
                                                 float* __restrict__ ve)
{
  int t = blockIdx.x*256 + threadIdx.x;
  if(t >= NRAYS*27) return;
  int ray = t/27, c = t%27;
  float v;
  if(c < 3) v = vd[ray*3 + c];
  else if(c < 15){
    int q = c - 3; int ci = q/4, p = q%4;
    v = sinf(vd[ray*3 + ci] * (float)(1 << p));
  } else {
    int q = c - 15; int ci = q/4, p = q%4;
    v = cosf(vd[ray*3 + ci] * (float)(1 << p));
  }
  ve[t] = v;
}

// ---------------- per-sample: mask + trilinear density->alpha + trilinear feat -
__global__ __launch_bounds__(256) void k_sample(const float* __restrict__ xyz,
    const void* __restrict__ mask, const float* __restrict__ density,
    const float* __restrict__ k0, const int* __restrict__ flag,
    float* __restrict__ alpha_w, unsigned short* __restrict__ feat_bf)
{
  int i = blockIdx.x*256 + threadIdx.x;
  float x = xyz[3*i+0], y = xyz[3*i+1], z = xyz[3*i+2];

  // nearest-neighbor mask lookup: round half-even matches jnp.round
  int mx = (int)rintf(x*79.5f + 79.5f); mx = min(max(mx,0), GXD-1);
  int my = (int)rintf(y*79.5f + 79.5f); my = min(max(my,0), GYD-1);
  int mz = (int)rintf(z*63.5f + 63.5f); mz = min(max(mz,0), GZD-1);
  int midx = mx*GYZ + my*GZD + mz;
  bool m = (*flag) ? (((const unsigned char*)mask)[midx] != 0)
                   : (((const int*)mask)[midx] != 0);

  // shared trilinear setup (align_corners=True)
  float tx = (x+1.f)*0.5f*(float)(GXD-1); tx = fminf(fmaxf(tx,0.f),(float)(GXD-1));
  float ty = (y+1.f)*0.5f*(float)(GYD-1); ty = fminf(fmaxf(ty,0.f),(float)(GYD-1));
  float tz = (z+1.f)*0.5f*(float)(GZD-1); tz = fminf(fmaxf(tz,0.f),(float)(GZD-1));
  int ix = min((int)tx, GXD-2), iy = min((int)ty, GYD-2), iz = min((int)tz, GZD-2);
  float fx = tx-ix, fy = ty-iy, fz = tz-iz;
  float wx[2] = {1.f-fx, fx}, wy[2] = {1.f-fy, fy}, wz[2] = {1.f-fz, fz};

  float d = 0.f;
  float f[12];
  #pragma unroll
  for(int c = 0; c < 12; ++c) f[c] = 0.f;

  #pragma unroll
  for(int dx = 0; dx < 2; ++dx)
  #pragma unroll
  for(int dy = 0; dy < 2; ++dy)
  #pragma unroll
  for(int dz = 0; dz < 2; ++dz){
    float w = wx[dx]*wy[dy]*wz[dz];
    int vox = (ix+dx)*GYZ + (iy+dy)*GZD + (iz+dz);
    d += w * density[vox];
    const float4* v = (const float4*)(k0 + (size_t)vox*12);
    float4 v0 = v[0], v1 = v[1], v2 = v[2];
    f[0] += w*v0.x; f[1] += w*v0.y; f[2]  += w*v0.z; f[3]  += w*v0.w;
    f[4] += w*v1.x; f[5] += w*v1.y; f[6]  += w*v1.z; f[7]  += w*v1.w;
    f[8] += w*v2.x; f[9] += w*v2.y; f[10] += w*v2.z; f[11] += w*v2.w;
  }

  float e = expf(d + ACT_SHIFT);
  float alpha = 1.f - rsqrtf(1.f + e);   // (1+e)^(-0.5), INTERVAL=0.5
  if(!m) alpha = 0.f;
  alpha_w[i] = alpha;

  #pragma unroll
  for(int c = 0; c < 12; ++c) feat_bf[(size_t)i*12 + c] = f2bf(f[c]);
}

// ---------------- per-ray segmented compositing (alpha -> weights, in place) ---
__global__ __launch_bounds__(256) void k_comp(const int* __restrict__ ray_id,
    float* __restrict__ alpha_w, float* __restrict__ out)
{
  int r = blockIdx.x*256 + threadIdx.x;
  if(r >= NRAYS) return;
  int lo = 0, hi = M_SAMPLES;
  while(lo < hi){ int mid = (lo+hi) >> 1; if(ray_id[mid] < r) lo = mid+1; else hi = mid; }
  float T = 1.f;
  int i = lo;
  while(i < M_SAMPLES && ray_id[i] == r){
    float a = alpha_w[i];
    alpha_w[i] = T * a;       // weight
    T *= (1.f - a);
    ++i;
  }
  out[3*r+0] = T; out[3*r+1] = T; out[3*r+2] = T;   // alphainv_last * white bg
}

// ---------------- fused MLP -----------------------------------------------------
template<int KPAD>
static __device__ inline void mlp_layer(const unsigned short* src, unsigned short* dst,
    const unsigned short* __restrict__ wt, const float* __restrict__ bias,
    int wave, int col, int q)
{
  constexpr int KS = KPAD/32;
  float bval = bias[wave*16 + col];
  bf16x8 bf[KS];
  const unsigned short* wrow = wt + (wave*16 + col)*KPAD + q*8;
  #pragma unroll
  for(int ks = 0; ks < KS; ++ks) bf[ks] = *(const bf16x8*)(wrow + ks*32);
  #pragma unroll
  for(int mt = 0; mt < 4; ++mt){
    f32x4 acc = {0.f, 0.f, 0.f, 0.f};
    const unsigned short* arow = src + (mt*16 + col)*LDSROW + q*8;
    #pragma unroll
    for(int ks = 0; ks < KS; ++ks){
      bf16x8 af = *(const bf16x8*)(arow + ks*32);
      acc = __builtin_amdgcn_mfma_f32_16x16x32_bf16(af, bf[ks], acc, 0, 0, 0);
    }
    #pragma unroll
    for(int r = 0; r < 4; ++r){
      float v = acc[r] + bval;
      v = fmaxf(v, 0.f);
      dst[(mt*16 + q*4 + r)*LDSROW + wave*16 + col] = f2bf(v);
    }
  }
}

__global__ __launch_bounds__(512) void k_mlp(const float* __restrict__ xyz,
    const int* __restrict__ ray_id, const unsigned short* __restrict__ feat_bf,
    const float* __restrict__ weights,
    const unsigned short* __restrict__ wt0, const unsigned short* __restrict__ wt1,
    const unsigned short* __restrict__ wt2,
    const float* __restrict__ b0, const float* __restrict__ b1,
    const float* __restrict__ b2,
    const float* __restrict__ Wr, const float* __restrict__ br,
    const float* __restrict__ ve, float* __restrict__ out)
{
  __shared__ alignas(16) unsigned short hA[64*LDSROW];
  __shared__ alignas(16) unsigned short hB[64*LDSROW];
  __shared__ float w_s[64];
  __shared__ int ray_s[64];

  int tid = threadIdx.x;
  int s = tid & 63, part = tid >> 6;
  int i = blockIdx.x*64 + s;
  float x = xyz[3*i+0], y = xyz[3*i+1], z = xyz[3*i+2];

  // build h0[s][0..95]: feat(12) | xyz(3) | sin(30) | cos(30) | zeros(75..95)
  int c0 = part*12;
  for(int c = c0; c < c0+12; ++c){
    unsigned short hv;
    if(c < 12)       hv = feat_bf[(size_t)i*12 + c];
    else if(c < 15)  hv = f2bf(c == 12 ? x : (c == 13 ? y : z));
    else if(c < 75){
      int q2 = (c < 45) ? (c-15) : (c-45);
      int ci = q2/10, p = q2%10;
      float xv = (ci == 0) ? x : ((ci == 1) ? y : z);
      float arg = xv * (float)(1 << p);
      hv = f2bf((c < 45) ? sinf(arg) : cosf(arg));
    } else hv = 0;
    hA[s*LDSROW + c] = hv;
  }
  if(part == 0){ w_s[s] = weights[i]; ray_s[s] = ray_id[i]; }
  __syncthreads();

  int lane = tid & 63, wave = tid >> 6, col = lane & 15, q = lane >> 4;
  mlp_layer<96 >(hA, hB, wt0, b0, wave, col, q);  __syncthreads();
  mlp_layer<128>(hB, hA, wt1, b1, wave, col, q);  __syncthreads();
  mlp_layer<128>(hA, hB, wt2, b2, wave, col, q);  __syncthreads();

  // rgb head: 155 x 3, threads (s, channel)
  if(tid < 192){
    int ss = tid & 63, c = tid >> 6;
    int ray = ray_s[ss];
    float acc = br[c];
    #pragma unroll 8
    for(int k = 0; k < 128; ++k) acc += bf2f(hB[ss*LDSROW + k]) * Wr[k*3 + c];
    #pragma unroll
    for(int k = 0; k < 27; ++k)  acc += ve[ray*27 + k] * Wr[(128+k)*3 + c];
    float rgb = 1.f / (1.f + expf(-acc));
    atomicAdd(&out[ray*3 + c], w_s[ss] * rgb);
  }
}

// ---------------- host ----------------------------------------------------------
extern "C" void kernel_launch(void* const* d_in, const int* in_sizes, int n_in,
                              void* d_out, int out_size, void* d_ws, size_t ws_size,
                              hipStream_t stream)
{
  const float* xyz      = (const float*)d_in[0];
  const int*   ray_id   = (const int*)  d_in[1];
  const float* viewdirs = (const float*)d_in[2];
  const void*  mask     =               d_in[3];
  const float* density  = (const float*)d_in[4];
  const float* k0       = (const float*)d_in[5];
  const float* W0 = (const float*)d_in[6];  const float* b0 = (const float*)d_in[7];
  const float* W1 = (const float*)d_in[8];  const float* b1 = (const float*)d_in[9];
  const float* W2 = (const float*)d_in[10]; const float* b2 = (const float*)d_in[11];
  const float* Wr = (const float*)d_in[12]; const float* br = (const float*)d_in[13];
  float* out = (float*)d_out;

  char* ws = (char*)d_ws;
  size_t off = 0;
  auto take = [&](size_t nbytes) -> void* {
    void* p = ws + off;
    off = (off + nbytes + 255) & ~(size_t)255;
    return p;
  };
  int*            flag    = (int*)           take(4);
  unsigned short* wt0     = (unsigned short*)take(128*96*2);
  unsigned short* wt1     = (unsigned short*)take(128*128*2);
  unsigned short* wt2     = (unsigned short*)take(128*128*2);
  float*          ve      = (float*)         take((size_t)NRAYS*27*4);
  float*          alpha_w = (float*)         take((size_t)M_SAMPLES*4);
  unsigned short* feat_bf = (unsigned short*)take((size_t)M_SAMPLES*12*2);

  k_detect <<<1,   64,  0, stream>>>((const unsigned int*)mask, flag);
  k_prep_w <<<176, 256, 0, stream>>>(W0, W1, W2, wt0, wt1, wt2);
  k_viewemb<<<864, 256, 0, stream>>>(viewdirs, ve);
  k_sample <<<M_SAMPLES/256, 256, 0, stream>>>(xyz, mask, density, k0, flag, alpha_w, feat_bf);
  k_comp   <<<NRAYS/256, 256, 0, stream>>>(ray_id, alpha_w, out);
  k_mlp    <<<M_SAMPLES/64, 512, 0, stream>>>(xyz, ray_id, feat_bf, alpha_w,
                                              wt0, wt1, wt2, b0, b1, b2, Wr, br, ve, out);
}

// Round 2
// 649.348 us; speedup vs baseline: 1.1902x; 1.1902x over previous
//
#include <hip/hip_runtime.h>
#include <hip/hip_bf16.h>

#define M_SAMPLES 524288
#define NRAYS 8192
#define GXD 160
#define GYD 160
#define GZD 128
#define GYZ (GYD*GZD)
#define ACT_SHIFT -13.81550955796f
#define ROWA 136      // hA leading dim (96 or 128 cols + pad), 272B = 16*17
#define ROWB 168      // hB leading dim (128 h cols + 27 ve + 5 pad), 336B = 16*21

typedef __bf16 bf16x8 __attribute__((ext_vector_type(8)));
typedef float f32x4 __attribute__((ext_vector_type(4)));

static __device__ inline unsigned short f2bf(float f){
  __hip_bfloat16 h = __float2bfloat16(f);
  unsigned short u; __builtin_memcpy(&u, &h, 2); return u;
}

// ---------------- mask dtype detection (numpy bool bytes vs int32) -------------
__global__ void k_detect(const unsigned int* __restrict__ mw, int* __restrict__ flag){
  if(threadIdx.x == 0){
    int f = 0;
    for(int i = 0; i < 64; ++i) if(mw[i] > 1u) f = 1;
    *flag = f;   // 1 = byte format, 0 = int32 format
  }
}

// ---------------- weight transpose + bf16 convert ------------------------------
// wt0: [128][96] (k>=75 zero), wt1/wt2: [128][128], wtr: [16][160] (rows>=3, k>=155 zero)
__global__ __launch_bounds__(256) void k_prep_w(const float* __restrict__ W0,
    const float* __restrict__ W1, const float* __restrict__ W2,
    const float* __restrict__ Wr,
    unsigned short* __restrict__ wt0, unsigned short* __restrict__ wt1,
    unsigned short* __restrict__ wt2, unsigned short* __restrict__ wtr)
{
  int t = blockIdx.x*256 + threadIdx.x;
  if(t < 128*96){
    int n = t/96, k = t%96;
    wt0[t] = f2bf((k < 75) ? W0[k*128 + n] : 0.f);
  } else if(t < 128*96 + 16384){
    int j = t - 128*96; int n = j/128, k = j%128;
    wt1[j] = f2bf(W1[k*128 + n]);
  } else if(t < 128*96 + 32768){
    int j = t - 128*96 - 16384; int n = j/128, k = j%128;
    wt2[j] = f2bf(W2[k*128 + n]);
  } else if(t < 128*96 + 32768 + 16*160){
    int j = t - 128*96 - 32768; int n = j/160, k = j%160;
    wtr[j] = f2bf((n < 3 && k < 155) ? Wr[k*3 + n] : 0.f);
  }
}

// ---------------- per-ray view-dir positional embedding ------------------------
__global__ __launch_bounds__(256) void k_viewemb(const float* __restrict__ vd,
                                                 float* __restrict__ ve)
{
  int t = blockIdx.x*256 + threadIdx.x;
  if(t >= NRAYS*27) return;
  int ray = t/27, c = t%27;
  float v;
  if(c < 3) v = vd[ray*3 + c];
  else if(c < 15){
    int q = c - 3; int ci = q/4, p = q%4;
    v = sinf(vd[ray*3 + ci] * (float)(1 << p));
  } else {
    int q = c - 15; int ci = q/4, p = q%4;
    v = cosf(vd[ray*3 + ci] * (float)(1 << p));
  }
  ve[t] = v;
}

// ---------------- per-sample: mask + trilinear density->alpha + trilinear feat -
__global__ __launch_bounds__(256) void k_sample(const float* __restrict__ xyz,
    const void* __restrict__ mask, const float* __restrict__ density,
    const float* __restrict__ k0, const int* __restrict__ flag,
    float* __restrict__ alpha_w, unsigned int* __restrict__ feat_bf)
{
  int i = blockIdx.x*256 + threadIdx.x;
  float x = xyz[3*i+0], y = xyz[3*i+1], z = xyz[3*i+2];

  int mx = (int)rintf(x*79.5f + 79.5f); mx = min(max(mx,0), GXD-1);
  int my = (int)rintf(y*79.5f + 79.5f); my = min(max(my,0), GYD-1);
  int mz = (int)rintf(z*63.5f + 63.5f); mz = min(max(mz,0), GZD-1);
  int midx = mx*GYZ + my*GZD + mz;
  bool m = (*flag) ? (((const unsigned char*)mask)[midx] != 0)
                   : (((const int*)mask)[midx] != 0);

  float tx = (x+1.f)*0.5f*(float)(GXD-1); tx = fminf(fmaxf(tx,0.f),(float)(GXD-1));
  float ty = (y+1.f)*0.5f*(float)(GYD-1); ty = fminf(fmaxf(ty,0.f),(float)(GYD-1));
  float tz = (z+1.f)*0.5f*(float)(GZD-1); tz = fminf(fmaxf(tz,0.f),(float)(GZD-1));
  int ix = min((int)tx, GXD-2), iy = min((int)ty, GYD-2), iz = min((int)tz, GZD-2);
  float fx = tx-ix, fy = ty-iy, fz = tz-iz;
  float wx[2] = {1.f-fx, fx}, wy[2] = {1.f-fy, fy};
  float wz0 = 1.f-fz, wz1 = fz;

  float d = 0.f;
  float f[12];
  #pragma unroll
  for(int c = 0; c < 12; ++c) f[c] = 0.f;

  // dz=0/1 corners are contiguous (48B k0 rows, 16B-aligned) -> paired loads
  #pragma unroll
  for(int dx = 0; dx < 2; ++dx)
  #pragma unroll
  for(int dy = 0; dy < 2; ++dy){
    float wxy = wx[dx]*wy[dy];
    int vox = (ix+dx)*GYZ + (iy+dy)*GZD + iz;
    d += wxy*(wz0*density[vox] + wz1*density[vox+1]);
    const float4* v = (const float4*)(k0 + (size_t)vox*12);
    float4 a0 = v[0], a1 = v[1], a2 = v[2];
    float4 c0 = v[3], c1 = v[4], c2 = v[5];
    float w0 = wxy*wz0, w1 = wxy*wz1;
    f[0] += w0*a0.x + w1*c0.x;  f[1] += w0*a0.y + w1*c0.y;
    f[2] += w0*a0.z + w1*c0.z;  f[3] += w0*a0.w + w1*c0.w;
    f[4] += w0*a1.x + w1*c1.x;  f[5] += w0*a1.y + w1*c1.y;
    f[6] += w0*a1.z + w1*c1.z;  f[7] += w0*a1.w + w1*c1.w;
    f[8] += w0*a2.x + w1*c2.x;  f[9] += w0*a2.y + w1*c2.y;
    f[10]+= w0*a2.z + w1*c2.z;  f[11]+= w0*a2.w + w1*c2.w;
  }

  float e = expf(d + ACT_SHIFT);
  float alpha = 1.f - rsqrtf(1.f + e);   // (1+e)^(-0.5), INTERVAL=0.5
  if(!m) alpha = 0.f;
  alpha_w[i] = alpha;

  #pragma unroll
  for(int c = 0; c < 6; ++c){
    unsigned int lo = f2bf(f[2*c]), hi = f2bf(f[2*c+1]);
    feat_bf[(size_t)i*6 + c] = lo | (hi << 16);
  }
}

// ---------------- per-ray segmented compositing (alpha -> weights, in place) ---
__global__ __launch_bounds__(256) void k_comp(const int* __restrict__ ray_id,
    float* __restrict__ alpha_w, float* __restrict__ out)
{
  int r = blockIdx.x*256 + threadIdx.x;
  if(r >= NRAYS) return;
  int lo = 0, hi = M_SAMPLES;
  while(lo < hi){ int mid = (lo+hi) >> 1; if(ray_id[mid] < r) lo = mid+1; else hi = mid; }
  float T = 1.f;
  int i = lo;
  while(i < M_SAMPLES && ray_id[i] == r){
    float a = alpha_w[i];
    alpha_w[i] = T * a;       // weight
    T *= (1.f - a);
    ++i;
  }
  out[3*r+0] = T; out[3*r+1] = T; out[3*r+2] = T;   // alphainv_last * white bg
}

// ---------------- fused MLP -----------------------------------------------------
template<int KPAD, int SROW, int DROW>
static __device__ inline void mlp_layer(const unsigned short* src, unsigned short* dst,
    const unsigned short* __restrict__ wt, const float* __restrict__ bias,
    int wave, int col, int q)
{
  constexpr int KS = KPAD/32;
  float bval = bias[wave*16 + col];
  bf16x8 bf[KS];
  const unsigned short* wrow = wt + (wave*16 + col)*KPAD + q*8;
  #pragma unroll
  for(int ks = 0; ks < KS; ++ks) bf[ks] = *(const bf16x8*)(wrow + ks*32);
  #pragma unroll
  for(int mt = 0; mt < 4; ++mt){
    f32x4 acc = {0.f, 0.f, 0.f, 0.f};
    const unsigned short* arow = src + (mt*16 + col)*SROW + q*8;
    #pragma unroll
    for(int ks = 0; ks < KS; ++ks){
      bf16x8 af = *(const bf16x8*)(arow + ks*32);
      acc = __builtin_amdgcn_mfma_f32_16x16x32_bf16(af, bf[ks], acc, 0, 0, 0);
    }
    #pragma unroll
    for(int r = 0; r < 4; ++r){
      float v = fmaxf(acc[r] + bval, 0.f);
      dst[(mt*16 + q*4 + r)*DROW + wave*16 + col] = f2bf(v);
    }
  }
}

__global__ __launch_bounds__(512) void k_mlp(const float* __restrict__ xyz,
    const int* __restrict__ ray_id, const unsigned int* __restrict__ feat_bf,
    const float* __restrict__ weights,
    const unsigned short* __restrict__ wt0, const unsigned short* __restrict__ wt1,
    const unsigned short* __restrict__ wt2, const unsigned short* __restrict__ wtr,
    const float* __restrict__ b0, const float* __restrict__ b1,
    const float* __restrict__ b2, const float* __restrict__ br,
    const float* __restrict__ ve, float* __restrict__ out)
{
  __shared__ alignas(16) unsigned short hA[64*ROWA];
  __shared__ alignas(16) unsigned short hB[64*ROWB];
  __shared__ float red[64*3];
  __shared__ float w_s[64];
  __shared__ int ray_s[64];

  int tid = threadIdx.x;
  int s = tid & 63, part = tid >> 6;
  int i = blockIdx.x*64 + s;
  float x = xyz[3*i+0], y = xyz[3*i+1], z = xyz[3*i+2];

  // phase 0: h0[s][0..95] = feat(12)|xyz(3)|sin(30)|cos(30)|zeros ; hB ve cols; w/ray
  int c0 = part*12;
  for(int c = c0; c < c0+12; ++c){
    unsigned short hv;
    if(c < 12){
      unsigned int pk = feat_bf[(size_t)i*6 + (c>>1)];
      hv = (unsigned short)((c & 1) ? (pk >> 16) : pk);
    }
    else if(c < 15)  hv = f2bf(c == 12 ? x : (c == 13 ? y : z));
    else if(c < 75){
      int q2 = (c < 45) ? (c-15) : (c-45);
      int ci = q2/10, p = q2%10;
      float xv = (ci == 0) ? x : ((ci == 1) ? y : z);
      float arg = xv * (float)(1 << p);
      hv = f2bf((c < 45) ? sinf(arg) : cosf(arg));
    } else hv = 0;
    hA[s*ROWA + c] = hv;
  }
  // ve -> hB cols 128..159 (27 real + 5 zero)
  for(int idx = tid; idx < 64*32; idx += 512){
    int ss = idx >> 5, c = idx & 31;
    int ray = ray_id[blockIdx.x*64 + ss];
    hB[ss*ROWB + 128 + c] = (c < 27) ? f2bf(ve[ray*27 + c]) : (unsigned short)0;
  }
  if(part == 0){ w_s[s] = weights[i]; ray_s[s] = ray_id[i]; }
  __syncthreads();

  int lane = tid & 63, wave = tid >> 6, col = lane & 15, q = lane >> 4;
  mlp_layer< 96, ROWA, ROWB>(hA, hB, wt0, b0, wave, col, q);  __syncthreads();
  mlp_layer<128, ROWB, ROWA>(hB, hA, wt1, b1, wave, col, q);  __syncthreads();
  mlp_layer<128, ROWA, ROWB>(hA, hB, wt2, b2, wave, col, q);  __syncthreads();

  // phase 4: rgb head via MFMA, K=160 (128 h + 27 ve + 5 pad), waves 0..3 = m-tiles
  if(wave < 4){
    int mt = wave;
    f32x4 acc = {0.f, 0.f, 0.f, 0.f};
    const unsigned short* arow = hB + (mt*16 + col)*ROWB + q*8;
    const unsigned short* wrow = wtr + col*160 + q*8;
    #pragma unroll
    for(int ks = 0; ks < 5; ++ks){
      bf16x8 af = *(const bf16x8*)(arow + ks*32);
      bf16x8 bfr = *(const bf16x8*)(wrow + ks*32);
      acc = __builtin_amdgcn_mfma_f32_16x16x32_bf16(af, bfr, acc, 0, 0, 0);
    }
    if(col < 3){
      #pragma unroll
      for(int r = 0; r < 4; ++r){
        int sl = mt*16 + q*4 + r;
        float v = acc[r] + br[col];
        float sg = 1.f / (1.f + expf(-v));
        red[sl*3 + col] = w_s[sl] * sg;
      }
    }
  }
  __syncthreads();

  // phase 5: segmented reduce over sorted ray ids, one atomic per segment
  if(tid < 192){
    int c = tid >> 6, ss = tid & 63;
    int sray = ray_s[ss];
    if(ss == 0 || ray_s[ss-1] != sray){
      float sum = 0.f;
      int j = ss;
      while(j < 64 && ray_s[j] == sray){ sum += red[j*3 + c]; ++j; }
      atomicAdd(&out[sray*3 + c], sum);
    }
  }
}

// ---------------- host ----------------------------------------------------------
extern "C" void kernel_launch(void* const* d_in, const int* in_sizes, int n_in,
                              void* d_out, int out_size, void* d_ws, size_t ws_size,
                              hipStream_t stream)
{
  const float* xyz      = (const float*)d_in[0];
  const int*   ray_id   = (const int*)  d_in[1];
  const float* viewdirs = (const float*)d_in[2];
  const void*  mask     =               d_in[3];
  const float* density  = (const float*)d_in[4];
  const float* k0       = (const float*)d_in[5];
  const float* W0 = (const float*)d_in[6];  const float* b0 = (const float*)d_in[7];
  const float* W1 = (const float*)d_in[8];  const float* b1 = (const float*)d_in[9];
  const float* W2 = (const float*)d_in[10]; const float* b2 = (const float*)d_in[11];
  const float* Wr = (const float*)d_in[12]; const float* br = (const float*)d_in[13];
  float* out = (float*)d_out;

  char* ws = (char*)d_ws;
  size_t off = 0;
  auto take = [&](size_t nbytes) -> void* {
    void* p = ws + off;
    off = (off + nbytes + 255) & ~(size_t)255;
    return p;
  };
  int*            flag    = (int*)           take(4);
  unsigned short* wt0     = (unsigned short*)take(128*96*2);
  unsigned short* wt1     = (unsigned short*)take(128*128*2);
  unsigned short* wt2     = (unsigned short*)take(128*128*2);
  unsigned short* wtr     = (unsigned short*)take(16*160*2);
  float*          ve      = (float*)         take((size_t)NRAYS*27*4);
  float*          alpha_w = (float*)         take((size_t)M_SAMPLES*4);
  unsigned int*   feat_bf = (unsigned int*)  take((size_t)M_SAMPLES*6*4);

  k_detect <<<1,   64,  0, stream>>>((const unsigned int*)mask, flag);
  k_prep_w <<<186, 256, 0, stream>>>(W0, W1, W2, Wr, wt0, wt1, wt2, wtr);
  k_viewemb<<<864, 256, 0, stream>>>(viewdirs, ve);
  k_sample <<<M_SAMPLES/256, 256, 0, stream>>>(xyz, mask, density, k0, flag, alpha_w, feat_bf);
  k_comp   <<<NRAYS/256, 256, 0, stream>>>(ray_id, alpha_w, out);
  k_mlp    <<<M_SAMPLES/64, 512, 0, stream>>>(xyz, ray_id, feat_bf, alpha_w,
                                              wt0, wt1, wt2, wtr, b0, b1, b2, br, ve, out);
}

// Round 4
// 617.085 us; speedup vs baseline: 1.2524x; 1.0523x over previous
//
#include <hip/hip_runtime.h>
#include <hip/hip_bf16.h>

#define M_SAMPLES 524288
#define NRAYS 8192
#define GXD 160
#define GYD 160
#define GZD 128
#define GYZ (GYD*GZD)
#define NVOX (GXD*GYD*GZD)
#define ACT_SHIFT -13.81550955796f
#define ROWA 136      // hA leading dim, 272B = 16*17
#define ROWB 168      // hB leading dim (128 h + 27 ve + 5 pad), 336B = 16*21

typedef __bf16 bf16x8 __attribute__((ext_vector_type(8)));
typedef float f32x4 __attribute__((ext_vector_type(4)));
typedef float f32x16 __attribute__((ext_vector_type(16)));

static __device__ inline unsigned short f2bf(float f){
  __hip_bfloat16 h = __float2bfloat16(f);
  unsigned short u; __builtin_memcpy(&u, &h, 2); return u;
}
static __device__ inline float flo(unsigned int u){ return __uint_as_float(u << 16); }
static __device__ inline float fhi(unsigned int u){ return __uint_as_float(u & 0xffff0000u); }
static __device__ inline unsigned int packbf(float a, float b){
  return (unsigned int)f2bf(a) | ((unsigned int)f2bf(b) << 16);
}

// ---------------- mask dtype detection (numpy bool bytes vs int32) -------------
__global__ void k_detect(const unsigned int* __restrict__ mw, int* __restrict__ flag){
  if(threadIdx.x == 0){
    int f = 0;
    for(int i = 0; i < 64; ++i) if(mw[i] > 1u) f = 1;
    *flag = f;   // 1 = byte format, 0 = int32 format
  }
}

// ---------------- weight transpose + bf16 convert ------------------------------
__global__ __launch_bounds__(256) void k_prep_w(const float* __restrict__ W0,
    const float* __restrict__ W1, const float* __restrict__ W2,
    const float* __restrict__ Wr,
    unsigned short* __restrict__ wt0, unsigned short* __restrict__ wt1,
    unsigned short* __restrict__ wt2, unsigned short* __restrict__ wtr)
{
  int t = blockIdx.x*256 + threadIdx.x;
  if(t < 128*96){
    int n = t/96, k = t%96;
    wt0[t] = f2bf((k < 75) ? W0[k*128 + n] : 0.f);
  } else if(t < 128*96 + 16384){
    int j = t - 128*96; int n = j/128, k = j%128;
    wt1[j] = f2bf(W1[k*128 + n]);
  } else if(t < 128*96 + 32768){
    int j = t - 128*96 - 16384; int n = j/128, k = j%128;
    wt2[j] = f2bf(W2[k*128 + n]);
  } else if(t < 128*96 + 32768 + 16*160){
    int j = t - 128*96 - 32768; int n = j/160, k = j%160;
    wtr[j] = f2bf((n < 3 && k < 155) ? Wr[k*3 + n] : 0.f);
  }
}

// ---------------- per-ray view-dir positional embedding ------------------------
__global__ __launch_bounds__(256) void k_viewemb(const float* __restrict__ vd,
                                                 float* __restrict__ ve)
{
  int t = blockIdx.x*256 + threadIdx.x;
  if(t >= NRAYS*27) return;
  int ray = t/27, c = t%27;
  float v;
  if(c < 3) v = vd[ray*3 + c];
  else if(c < 15){
    int q = c - 3; int ci = q/4, p = q%4;
    v = sinf(vd[ray*3 + ci] * (float)(1 << p));
  } else {
    int q = c - 15; int ci = q/4, p = q%4;
    v = cosf(vd[ray*3 + ci] * (float)(1 << p));
  }
  ve[t] = v;
}

// ---------------- voxel repack: density f32 + 12 bf16 feats = 32 B/voxel -------
__global__ __launch_bounds__(256) void k_repack(const float* __restrict__ density,
    const float* __restrict__ k0, uint4* __restrict__ packed)
{
  int v = blockIdx.x*256 + threadIdx.x;
  if(v >= NVOX) return;
  float d = density[v];
  const float4* kp = (const float4*)(k0 + (size_t)v*12);
  float4 a = kp[0], b = kp[1], c = kp[2];
  uint4 o0, o1;
  o0.x = __float_as_uint(d);
  o0.y = packbf(a.x, a.y); o0.z = packbf(a.z, a.w); o0.w = packbf(b.x, b.y);
  o1.x = packbf(b.z, b.w); o1.y = packbf(c.x, c.y); o1.z = packbf(c.z, c.w);
  o1.w = 0;
  packed[(size_t)v*2]   = o0;
  packed[(size_t)v*2+1] = o1;
}

// ---------------- per-sample (packed path) -------------------------------------
__global__ __launch_bounds__(256) void k_sample_packed(const float* __restrict__ xyz,
    const void* __restrict__ mask, const uint4* __restrict__ packed,
    const int* __restrict__ flag,
    float* __restrict__ alpha_w, unsigned int* __restrict__ feat_bf)
{
  int i = blockIdx.x*256 + threadIdx.x;
  float x = xyz[3*i+0], y = xyz[3*i+1], z = xyz[3*i+2];

  int mx = (int)rintf(x*79.5f + 79.5f); mx = min(max(mx,0), GXD-1);
  int my = (int)rintf(y*79.5f + 79.5f); my = min(max(my,0), GYD-1);
  int mz = (int)rintf(z*63.5f + 63.5f); mz = min(max(mz,0), GZD-1);
  int midx = mx*GYZ + my*GZD + mz;
  bool m = (*flag) ? (((const unsigned char*)mask)[midx] != 0)
                   : (((const int*)mask)[midx] != 0);

  float tx = (x+1.f)*0.5f*(float)(GXD-1); tx = fminf(fmaxf(tx,0.f),(float)(GXD-1));
  float ty = (y+1.f)*0.5f*(float)(GYD-1); ty = fminf(fmaxf(ty,0.f),(float)(GYD-1));
  float tz = (z+1.f)*0.5f*(float)(GZD-1); tz = fminf(fmaxf(tz,0.f),(float)(GZD-1));
  int ix = min((int)tx, GXD-2), iy = min((int)ty, GYD-2), iz = min((int)tz, GZD-2);
  float fx = tx-ix, fy = ty-iy, fz = tz-iz;
  float wx[2] = {1.f-fx, fx}, wy[2] = {1.f-fy, fy};
  float wz0 = 1.f-fz, wz1 = fz;

  float d = 0.f;
  float f[12];
  #pragma unroll
  for(int c = 0; c < 12; ++c) f[c] = 0.f;

  #pragma unroll
  for(int dx = 0; dx < 2; ++dx)
  #pragma unroll
  for(int dy = 0; dy < 2; ++dy){
    float wxy = wx[dx]*wy[dy];
    float w0 = wxy*wz0, w1 = wxy*wz1;
    size_t vox = (size_t)((ix+dx)*GYZ + (iy+dy)*GZD + iz);
    const uint4* pv = packed + vox*2;
    uint4 q0 = pv[0], q1 = pv[1], q2 = pv[2], q3 = pv[3];
    d += w0*__uint_as_float(q0.x) + w1*__uint_as_float(q2.x);
    f[0]  += w0*flo(q0.y) + w1*flo(q2.y);  f[1]  += w0*fhi(q0.y) + w1*fhi(q2.y);
    f[2]  += w0*flo(q0.z) + w1*flo(q2.z);  f[3]  += w0*fhi(q0.z) + w1*fhi(q2.z);
    f[4]  += w0*flo(q0.w) + w1*flo(q2.w);  f[5]  += w0*fhi(q0.w) + w1*fhi(q2.w);
    f[6]  += w0*flo(q1.x) + w1*flo(q3.x);  f[7]  += w0*fhi(q1.x) + w1*fhi(q3.x);
    f[8]  += w0*flo(q1.y) + w1*flo(q3.y);  f[9]  += w0*fhi(q1.y) + w1*fhi(q3.y);
    f[10] += w0*flo(q1.z) + w1*flo(q3.z);  f[11] += w0*fhi(q1.z) + w1*fhi(q3.z);
  }

  float e = expf(d + ACT_SHIFT);
  float alpha = 1.f - rsqrtf(1.f + e);   // (1+e)^(-0.5), INTERVAL=0.5
  if(!m) alpha = 0.f;
  alpha_w[i] = alpha;

  #pragma unroll
  for(int c = 0; c < 6; ++c)
    feat_bf[(size_t)i*6 + c] = packbf(f[2*c], f[2*c+1]);
}

// ---------------- per-sample (fallback: direct f32 grids) ----------------------
__global__ __launch_bounds__(256) void k_sample_direct(const float* __restrict__ xyz,
    const void* __restrict__ mask, const float* __restrict__ density,
    const float* __restrict__ k0, const int* __restrict__ flag,
    float* __restrict__ alpha_w, unsigned int* __restrict__ feat_bf)
{
  int i = blockIdx.x*256 + threadIdx.x;
  float x = xyz[3*i+0], y = xyz[3*i+1], z = xyz[3*i+2];

  int mx = (int)rintf(x*79.5f + 79.5f); mx = min(max(mx,0), GXD-1);
  int my = (int)rintf(y*79.5f + 79.5f); my = min(max(my,0), GYD-1);
  int mz = (int)rintf(z*63.5f + 63.5f); mz = min(max(mz,0), GZD-1);
  int midx = mx*GYZ + my*GZD + mz;
  bool m = (*flag) ? (((const unsigned char*)mask)[midx] != 0)
                   : (((const int*)mask)[midx] != 0);

  float tx = (x+1.f)*0.5f*(float)(GXD-1); tx = fminf(fmaxf(tx,0.f),(float)(GXD-1));
  float ty = (y+1.f)*0.5f*(float)(GYD-1); ty = fminf(fmaxf(ty,0.f),(float)(GYD-1));
  float tz = (z+1.f)*0.5f*(float)(GZD-1); tz = fminf(fmaxf(tz,0.f),(float)(GZD-1));
  int ix = min((int)tx, GXD-2), iy = min((int)ty, GYD-2), iz = min((int)tz, GZD-2);
  float fx = tx-ix, fy = ty-iy, fz = tz-iz;
  float wx[2] = {1.f-fx, fx}, wy[2] = {1.f-fy, fy};
  float wz0 = 1.f-fz, wz1 = fz;

  float d = 0.f;
  float f[12];
  #pragma unroll
  for(int c = 0; c < 12; ++c) f[c] = 0.f;

  #pragma unroll
  for(int dx = 0; dx < 2; ++dx)
  #pragma unroll
  for(int dy = 0; dy < 2; ++dy){
    float wxy = wx[dx]*wy[dy];
    int vox = (ix+dx)*GYZ + (iy+dy)*GZD + iz;
    d += wxy*(wz0*density[vox] + wz1*density[vox+1]);
    const float4* v = (const float4*)(k0 + (size_t)vox*12);
    float4 a0 = v[0], a1 = v[1], a2 = v[2];
    float4 c0 = v[3], c1 = v[4], c2 = v[5];
    float w0 = wxy*wz0, w1 = wxy*wz1;
    f[0] += w0*a0.x + w1*c0.x;  f[1] += w0*a0.y + w1*c0.y;
    f[2] += w0*a0.z + w1*c0.z;  f[3] += w0*a0.w + w1*c0.w;
    f[4] += w0*a1.x + w1*c1.x;  f[5] += w0*a1.y + w1*c1.y;
    f[6] += w0*a1.z + w1*c1.z;  f[7] += w0*a1.w + w1*c1.w;
    f[8] += w0*a2.x + w1*c2.x;  f[9] += w0*a2.y + w1*c2.y;
    f[10]+= w0*a2.z + w1*c2.z;  f[11]+= w0*a2.w + w1*c2.w;
  }

  float e = expf(d + ACT_SHIFT);
  float alpha = 1.f - rsqrtf(1.f + e);
  if(!m) alpha = 0.f;
  alpha_w[i] = alpha;

  #pragma unroll
  for(int c = 0; c < 6; ++c)
    feat_bf[(size_t)i*6 + c] = packbf(f[2*c], f[2*c+1]);
}

// ---------------- per-ray compositing: one wave per ray, shfl prefix product ---
__global__ __launch_bounds__(256) void k_comp(const int* __restrict__ ray_id,
    float* __restrict__ alpha_w, float* __restrict__ out)
{
  int r = blockIdx.x*4 + (threadIdx.x >> 6);   // grid = NRAYS/4 blocks!
  int lane = threadIdx.x & 63;
  int lo = 0, hi = M_SAMPLES;
  while(lo < hi){ int mid = (lo+hi) >> 1; if(ray_id[mid] < r) lo = mid+1; else hi = mid; }
  int s = lo;
  int lo2 = s, hi2 = M_SAMPLES;
  while(lo2 < hi2){ int mid = (lo2+hi2) >> 1; if(ray_id[mid] < r+1) lo2 = mid+1; else hi2 = mid; }
  int e = lo2;

  float carry = 1.f;
  for(int base = s; base < e; base += 64){
    int idx = base + lane;
    float a = (idx < e) ? alpha_w[idx] : 0.f;
    float incl = 1.f - a;
    #pragma unroll
    for(int d2 = 1; d2 < 64; d2 <<= 1){
      float t = __shfl_up(incl, d2);
      if(lane >= d2) incl *= t;
    }
    float excl = __shfl_up(incl, 1);
    if(lane == 0) excl = 1.f;
    if(idx < e) alpha_w[idx] = carry * excl * a;   // weight, in place
    carry *= __shfl(incl, 63);
  }
  if(lane == 0){ out[3*r+0] = carry; out[3*r+1] = carry; out[3*r+2] = carry; }
}

// ---------------- fused MLP -----------------------------------------------------
// 32x32x16 MFMA with A=weights, B=activations -> D[neuron][sample]:
// col=lane&31=sample, row=(reg&3)+8*(reg>>2)+4*(lane>>5)=neuron -> 4-contig b64 writes
template<int KDIM, int SROW, int DROW>
static __device__ inline void layer32(const unsigned short* src, unsigned short* dst,
    const unsigned short* __restrict__ wt, const float* __restrict__ bias,
    int wave, int ln, int kh)
{
  constexpr int NS = KDIM/16;
  int tile_s = wave & 1, tile_n = wave >> 1;
  const unsigned short* wbase = wt + (tile_n*32 + ln)*KDIM + kh*8;
  const unsigned short* abase = src + (tile_s*32 + ln)*SROW + kh*8;
  f32x16 acc = {0.f,0.f,0.f,0.f,0.f,0.f,0.f,0.f,0.f,0.f,0.f,0.f,0.f,0.f,0.f,0.f};
  #pragma unroll
  for(int st = 0; st < NS; ++st){
    bf16x8 af = *(const bf16x8*)(wbase + st*16);
    bf16x8 bfr = *(const bf16x8*)(abase + st*16);
    acc = __builtin_amdgcn_mfma_f32_32x32x16_bf16(af, bfr, acc, 0, 0, 0);
  }
  int scol = tile_s*32 + ln;
  #pragma unroll
  for(int g = 0; g < 4; ++g){
    int n0 = tile_n*32 + g*8 + kh*4;
    float4 bv = *(const float4*)(bias + n0);
    unsigned long long o =
        (unsigned long long)f2bf(fmaxf(acc[4*g+0] + bv.x, 0.f))
      | ((unsigned long long)f2bf(fmaxf(acc[4*g+1] + bv.y, 0.f)) << 16)
      | ((unsigned long long)f2bf(fmaxf(acc[4*g+2] + bv.z, 0.f)) << 32)
      | ((unsigned long long)f2bf(fmaxf(acc[4*g+3] + bv.w, 0.f)) << 48);
    *(unsigned long long*)(dst + scol*DROW + n0) = o;
  }
}

__global__ __launch_bounds__(512) void k_mlp(const float* __restrict__ xyz,
    const int* __restrict__ ray_id, const unsigned int* __restrict__ feat_bf,
    const float* __restrict__ weights,
    const unsigned short* __restrict__ wt0, const unsigned short* __restrict__ wt1,
    const unsigned short* __restrict__ wt2, const unsigned short* __restrict__ wtr,
    const float* __restrict__ b0, const float* __restrict__ b1,
    const float* __restrict__ b2, const float* __restrict__ br,
    const float* __restrict__ ve, float* __restrict__ out)
{
  __shared__ alignas(16) unsigned short hA[64*ROWA];
  __shared__ alignas(16) unsigned short hB[64*ROWB];
  __shared__ float red[64*3];
  __shared__ float w_s[64];
  __shared__ int ray_s[64];

  int tid = threadIdx.x;
  int s = tid & 63, part = tid >> 6;
  int i = blockIdx.x*64 + s;
  float x = xyz[3*i+0], y = xyz[3*i+1], z = xyz[3*i+2];

  // phase 0: h0[s][0..95] = feat(12)|xyz(3)|sin(30)|cos(30)|zeros ; hB ve cols
  int c0 = part*12;
  for(int c = c0; c < c0+12; ++c){
    unsigned short hv;
    if(c < 12){
      unsigned int pk = feat_bf[(size_t)i*6 + (c>>1)];
      hv = (unsigned short)((c & 1) ? (pk >> 16) : pk);
    }
    else if(c < 15)  hv = f2bf(c == 12 ? x : (c == 13 ? y : z));
    else if(c < 75){
      int q2 = (c < 45) ? (c-15) : (c-45);
      int ci = q2/10, p = q2%10;
      float xv = (ci == 0) ? x : ((ci == 1) ? y : z);
      float arg = xv * (float)(1 << p);
      hv = f2bf((c < 45) ? __sinf(arg) : __cosf(arg));
    } else hv = 0;
    hA[s*ROWA + c] = hv;
  }
  for(int idx = tid; idx < 64*32; idx += 512){
    int ss = idx >> 5, c = idx & 31;
    int ray = ray_id[blockIdx.x*64 + ss];
    hB[ss*ROWB + 128 + c] = (c < 27) ? f2bf(ve[ray*27 + c]) : (unsigned short)0;
  }
  if(part == 0){ w_s[s] = weights[i]; ray_s[s] = ray_id[i]; }
  __syncthreads();

  int lane = tid & 63, wave = tid >> 6;
  int ln = lane & 31, kh = lane >> 5;
  layer32< 96, ROWA, ROWB>(hA, hB, wt0, b0, wave, ln, kh);  __syncthreads();
  layer32<128, ROWB, ROWA>(hB, hA, wt1, b1, wave, ln, kh);  __syncthreads();
  layer32<128, ROWA, ROWB>(hA, hB, wt2, b2, wave, ln, kh);  __syncthreads();

  // rgb head via 16x16x32 MFMA, K=160 (128 h + 27 ve + 5 pad), waves 0..3 = m-tiles
  int col = lane & 15, q = lane >> 4;
  if(wave < 4){
    int mt = wave;
    f32x4 acc = {0.f, 0.f, 0.f, 0.f};
    const unsigned short* arow = hB + (mt*16 + col)*ROWB + q*8;
    const unsigned short* wrow = wtr + col*160 + q*8;
    #pragma unroll
    for(int ks = 0; ks < 5; ++ks){
      bf16x8 af = *(const bf16x8*)(arow + ks*32);
      bf16x8 bfr = *(const bf16x8*)(wrow + ks*32);
      acc = __builtin_amdgcn_mfma_f32_16x16x32_bf16(af, bfr, acc, 0, 0, 0);
    }
    if(col < 3){
      #pragma unroll
      for(int r = 0; r < 4; ++r){
        int sl = mt*16 + q*4 + r;
        float v = acc[r] + br[col];
        float sg = 1.f / (1.f + expf(-v));
        red[sl*3 + col] = w_s[sl] * sg;
      }
    }
  }
  __syncthreads();

  // segmented reduce over sorted ray ids, one atomic per segment
  if(tid < 192){
    int c = tid >> 6, ss = tid & 63;
    int sray = ray_s[ss];
    if(ss == 0 || ray_s[ss-1] != sray){
      float sum = 0.f;
      int j = ss;
      while(j < 64 && ray_s[j] == sray){ sum += red[j*3 + c]; ++j; }
      atomicAdd(&out[sray*3 + c], sum);
    }
  }
}

// ---------------- host ----------------------------------------------------------
extern "C" void kernel_launch(void* const* d_in, const int* in_sizes, int n_in,
                              void* d_out, int out_size, void* d_ws, size_t ws_size,
                              hipStream_t stream)
{
  const float* xyz      = (const float*)d_in[0];
  const int*   ray_id   = (const int*)  d_in[1];
  const float* viewdirs = (const float*)d_in[2];
  const void*  mask     =               d_in[3];
  const float* density  = (const float*)d_in[4];
  const float* k0       = (const float*)d_in[5];
  const float* W0 = (const float*)d_in[6];  const float* b0 = (const float*)d_in[7];
  const float* W1 = (const float*)d_in[8];  const float* b1 = (const float*)d_in[9];
  const float* W2 = (const float*)d_in[10]; const float* b2 = (const float*)d_in[11];
  const float* Wr = (const float*)d_in[12]; const float* br = (const float*)d_in[13];
  float* out = (float*)d_out;

  char* ws = (char*)d_ws;
  size_t off = 0;
  auto take = [&](size_t nbytes) -> void* {
    void* p = ws + off;
    off = (off + nbytes + 255) & ~(size_t)255;
    return p;
  };
  int*            flag    = (int*)           take(4);
  unsigned short* wt0     = (unsigned short*)take(128*96*2);
  unsigned short* wt1     = (unsigned short*)take(128*128*2);
  unsigned short* wt2     = (unsigned short*)take(128*128*2);
  unsigned short* wtr     = (unsigned short*)take(16*160*2);
  float*          ve      = (float*)         take((size_t)NRAYS*27*4);
  float*          alpha_w = (float*)         take((size_t)M_SAMPLES*4);
  unsigned int*   feat_bf = (unsigned int*)  take((size_t)M_SAMPLES*6*4);
  uint4*          packed  = (uint4*)         take((size_t)NVOX*32);
  bool use_packed = (ws_size >= off);

  k_detect <<<1,   64,  0, stream>>>((const unsigned int*)mask, flag);
  k_prep_w <<<186, 256, 0, stream>>>(W0, W1, W2, Wr, wt0, wt1, wt2, wtr);
  k_viewemb<<<864, 256, 0, stream>>>(viewdirs, ve);
  if(use_packed){
    k_repack       <<<(NVOX+255)/256, 256, 0, stream>>>(density, k0, packed);
    k_sample_packed<<<M_SAMPLES/256, 256, 0, stream>>>(xyz, mask, packed, flag,
                                                       alpha_w, feat_bf);
  } else {
    k_sample_direct<<<M_SAMPLES/256, 256, 0, stream>>>(xyz, mask, density, k0, flag,
                                                       alpha_w, feat_bf);
  }
  k_comp   <<<NRAYS/4, 256, 0, stream>>>(ray_id, alpha_w, out);
  k_mlp    <<<M_SAMPLES/64, 512, 0, stream>>>(xyz, ray_id, feat_bf, alpha_w,
                                              wt0, wt1, wt2, wtr, b0, b1, b2, br, ve, out);
}

// Round 5
// 608.531 us; speedup vs baseline: 1.2700x; 1.0141x over previous
//
#include <hip/hip_runtime.h>
#include <hip/hip_bf16.h>

#define M_SAMPLES 524288
#define NRAYS 8192
#define GXD 160
#define GYD 160
#define GZD 128
#define GYZ (GYD*GZD)
#define NVOX (GXD*GYD*GZD)
#define ACT_SHIFT -13.81550955796f
#define ROWA 136      // hA leading dim, 272B = 17*16B (17 mod 8 = 1 -> conflict-free b128)
#define ROWB 168      // hB leading dim, 336B = 21*16B (21 mod 8 = 5 -> conflict-free b128)

typedef __bf16 bf16x8 __attribute__((ext_vector_type(8)));
typedef float f32x4 __attribute__((ext_vector_type(4)));
typedef float f32x16 __attribute__((ext_vector_type(16)));

static __device__ inline unsigned short f2bf(float f){
  __hip_bfloat16 h = __float2bfloat16(f);
  unsigned short u; __builtin_memcpy(&u, &h, 2); return u;
}
static __device__ inline float flo(unsigned int u){ return __uint_as_float(u << 16); }
static __device__ inline float fhi(unsigned int u){ return __uint_as_float(u & 0xffff0000u); }

#if defined(__has_builtin)
#if __has_builtin(__builtin_amdgcn_cvt_pk_bf16_f32)
#define HAVE_PK_BF16 1
#endif
#endif

static __device__ inline unsigned int packbf(float a, float b){
#ifdef HAVE_PK_BF16
  typedef __bf16 bf16v2 __attribute__((ext_vector_type(2)));
  bf16v2 r = __builtin_amdgcn_cvt_pk_bf16_f32(a, b);
  unsigned int u; __builtin_memcpy(&u, &r, 4); return u;
#else
  return (unsigned int)f2bf(a) | ((unsigned int)f2bf(b) << 16);
#endif
}

// ---------------- mask dtype detection (numpy bool bytes vs int32) -------------
__global__ void k_detect(const unsigned int* __restrict__ mw, int* __restrict__ flag){
  if(threadIdx.x == 0){
    int f = 0;
    for(int i = 0; i < 64; ++i) if(mw[i] > 1u) f = 1;
    *flag = f;   // 1 = byte format, 0 = int32 format
  }
}

// ---------------- weight transpose + bf16 convert ------------------------------
__global__ __launch_bounds__(256) void k_prep_w(const float* __restrict__ W0,
    const float* __restrict__ W1, const float* __restrict__ W2,
    const float* __restrict__ Wr,
    unsigned short* __restrict__ wt0, unsigned short* __restrict__ wt1,
    unsigned short* __restrict__ wt2, unsigned short* __restrict__ wtr)
{
  int t = blockIdx.x*256 + threadIdx.x;
  if(t < 128*96){
    int n = t/96, k = t%96;
    wt0[t] = f2bf((k < 75) ? W0[k*128 + n] : 0.f);
  } else if(t < 128*96 + 16384){
    int j = t - 128*96; int n = j/128, k = j%128;
    wt1[j] = f2bf(W1[k*128 + n]);
  } else if(t < 128*96 + 32768){
    int j = t - 128*96 - 16384; int n = j/128, k = j%128;
    wt2[j] = f2bf(W2[k*128 + n]);
  } else if(t < 128*96 + 32768 + 16*160){
    int j = t - 128*96 - 32768; int n = j/160, k = j%160;
    wtr[j] = f2bf((n < 3 && k < 155) ? Wr[k*3 + n] : 0.f);
  }
}

// ---------------- per-ray view-dir positional embedding ------------------------
__global__ __launch_bounds__(256) void k_viewemb(const float* __restrict__ vd,
                                                 float* __restrict__ ve)
{
  int t = blockIdx.x*256 + threadIdx.x;
  if(t >= NRAYS*27) return;
  int ray = t/27, c = t%27;
  float v;
  if(c < 3) v = vd[ray*3 + c];
  else if(c < 15){
    int q = c - 3; int ci = q/4, p = q%4;
    v = sinf(vd[ray*3 + ci] * (float)(1 << p));
  } else {
    int q = c - 15; int ci = q/4, p = q%4;
    v = cosf(vd[ray*3 + ci] * (float)(1 << p));
  }
  ve[t] = v;
}

// ---------------- voxel repack: density f32 + 12 bf16 feats = 32 B/voxel -------
__global__ __launch_bounds__(256) void k_repack(const float* __restrict__ density,
    const float* __restrict__ k0, uint4* __restrict__ packed)
{
  int v = blockIdx.x*256 + threadIdx.x;
  if(v >= NVOX) return;
  float d = density[v];
  const float4* kp = (const float4*)(k0 + (size_t)v*12);
  float4 a = kp[0], b = kp[1], c = kp[2];
  uint4 o0, o1;
  o0.x = __float_as_uint(d);
  o0.y = packbf(a.x, a.y); o0.z = packbf(a.z, a.w); o0.w = packbf(b.x, b.y);
  o1.x = packbf(b.z, b.w); o1.y = packbf(c.x, c.y); o1.z = packbf(c.z, c.w);
  o1.w = 0;
  packed[(size_t)v*2]   = o0;
  packed[(size_t)v*2+1] = o1;
}

// ---------------- per-sample (packed path) -------------------------------------
__global__ __launch_bounds__(256) void k_sample_packed(const float* __restrict__ xyz,
    const void* __restrict__ mask, const uint4* __restrict__ packed,
    const int* __restrict__ flag,
    float* __restrict__ alpha_w, unsigned int* __restrict__ feat_bf)
{
  int i = blockIdx.x*256 + threadIdx.x;
  float x = xyz[3*i+0], y = xyz[3*i+1], z = xyz[3*i+2];

  int mx = (int)rintf(x*79.5f + 79.5f); mx = min(max(mx,0), GXD-1);
  int my = (int)rintf(y*79.5f + 79.5f); my = min(max(my,0), GYD-1);
  int mz = (int)rintf(z*63.5f + 63.5f); mz = min(max(mz,0), GZD-1);
  int midx = mx*GYZ + my*GZD + mz;
  bool m = (*flag) ? (((const unsigned char*)mask)[midx] != 0)
                   : (((const int*)mask)[midx] != 0);

  float tx = (x+1.f)*0.5f*(float)(GXD-1); tx = fminf(fmaxf(tx,0.f),(float)(GXD-1));
  float ty = (y+1.f)*0.5f*(float)(GYD-1); ty = fminf(fmaxf(ty,0.f),(float)(GYD-1));
  float tz = (z+1.f)*0.5f*(float)(GZD-1); tz = fminf(fmaxf(tz,0.f),(float)(GZD-1));
  int ix = min((int)tx, GXD-2), iy = min((int)ty, GYD-2), iz = min((int)tz, GZD-2);
  float fx = tx-ix, fy = ty-iy, fz = tz-iz;
  float wx[2] = {1.f-fx, fx}, wy[2] = {1.f-fy, fy};
  float wz0 = 1.f-fz, wz1 = fz;

  float d = 0.f;
  float f[12];
  #pragma unroll
  for(int c = 0; c < 12; ++c) f[c] = 0.f;

  #pragma unroll
  for(int dx = 0; dx < 2; ++dx)
  #pragma unroll
  for(int dy = 0; dy < 2; ++dy){
    float wxy = wx[dx]*wy[dy];
    float w0 = wxy*wz0, w1 = wxy*wz1;
    size_t vox = (size_t)((ix+dx)*GYZ + (iy+dy)*GZD + iz);
    const uint4* pv = packed + vox*2;
    uint4 q0 = pv[0], q1 = pv[1], q2 = pv[2], q3 = pv[3];
    d += w0*__uint_as_float(q0.x) + w1*__uint_as_float(q2.x);
    f[0]  += w0*flo(q0.y) + w1*flo(q2.y);  f[1]  += w0*fhi(q0.y) + w1*fhi(q2.y);
    f[2]  += w0*flo(q0.z) + w1*flo(q2.z);  f[3]  += w0*fhi(q0.z) + w1*fhi(q2.z);
    f[4]  += w0*flo(q0.w) + w1*flo(q2.w);  f[5]  += w0*fhi(q0.w) + w1*fhi(q2.w);
    f[6]  += w0*flo(q1.x) + w1*flo(q3.x);  f[7]  += w0*fhi(q1.x) + w1*fhi(q3.x);
    f[8]  += w0*flo(q1.y) + w1*flo(q3.y);  f[9]  += w0*fhi(q1.y) + w1*fhi(q3.y);
    f[10] += w0*flo(q1.z) + w1*flo(q3.z);  f[11] += w0*fhi(q1.z) + w1*fhi(q3.z);
  }

  float e = expf(d + ACT_SHIFT);
  float alpha = 1.f - rsqrtf(1.f + e);   // (1+e)^(-0.5), INTERVAL=0.5
  if(!m) alpha = 0.f;
  alpha_w[i] = alpha;

  #pragma unroll
  for(int c = 0; c < 6; ++c)
    feat_bf[(size_t)i*6 + c] = packbf(f[2*c], f[2*c+1]);
}

// ---------------- per-sample (fallback: direct f32 grids) ----------------------
__global__ __launch_bounds__(256) void k_sample_direct(const float* __restrict__ xyz,
    const void* __restrict__ mask, const float* __restrict__ density,
    const float* __restrict__ k0, const int* __restrict__ flag,
    float* __restrict__ alpha_w, unsigned int* __restrict__ feat_bf)
{
  int i = blockIdx.x*256 + threadIdx.x;
  float x = xyz[3*i+0], y = xyz[3*i+1], z = xyz[3*i+2];

  int mx = (int)rintf(x*79.5f + 79.5f); mx = min(max(mx,0), GXD-1);
  int my = (int)rintf(y*79.5f + 79.5f); my = min(max(my,0), GYD-1);
  int mz = (int)rintf(z*63.5f + 63.5f); mz = min(max(mz,0), GZD-1);
  int midx = mx*GYZ + my*GZD + mz;
  bool m = (*flag) ? (((const unsigned char*)mask)[midx] != 0)
                   : (((const int*)mask)[midx] != 0);

  float tx = (x+1.f)*0.5f*(float)(GXD-1); tx = fminf(fmaxf(tx,0.f),(float)(GXD-1));
  float ty = (y+1.f)*0.5f*(float)(GYD-1); ty = fminf(fmaxf(ty,0.f),(float)(GYD-1));
  float tz = (z+1.f)*0.5f*(float)(GZD-1); tz = fminf(fmaxf(tz,0.f),(float)(GZD-1));
  int ix = min((int)tx, GXD-2), iy = min((int)ty, GYD-2), iz = min((int)tz, GZD-2);
  float fx = tx-ix, fy = ty-iy, fz = tz-iz;
  float wx[2] = {1.f-fx, fx}, wy[2] = {1.f-fy, fy};
  float wz0 = 1.f-fz, wz1 = fz;

  float d = 0.f;
  float f[12];
  #pragma unroll
  for(int c = 0; c < 12; ++c) f[c] = 0.f;

  #pragma unroll
  for(int dx = 0; dx < 2; ++dx)
  #pragma unroll
  for(int dy = 0; dy < 2; ++dy){
    float wxy = wx[dx]*wy[dy];
    int vox = (ix+dx)*GYZ + (iy+dy)*GZD + iz;
    d += wxy*(wz0*density[vox] + wz1*density[vox+1]);
    const float4* v = (const float4*)(k0 + (size_t)vox*12);
    float4 a0 = v[0], a1 = v[1], a2 = v[2];
    float4 c0 = v[3], c1 = v[4], c2 = v[5];
    float w0 = wxy*wz0, w1 = wxy*wz1;
    f[0] += w0*a0.x + w1*c0.x;  f[1] += w0*a0.y + w1*c0.y;
    f[2] += w0*a0.z + w1*c0.z;  f[3] += w0*a0.w + w1*c0.w;
    f[4] += w0*a1.x + w1*c1.x;  f[5] += w0*a1.y + w1*c1.y;
    f[6] += w0*a1.z + w1*c1.z;  f[7] += w0*a1.w + w1*c1.w;
    f[8] += w0*a2.x + w1*c2.x;  f[9] += w0*a2.y + w1*c2.y;
    f[10]+= w0*a2.z + w1*c2.z;  f[11]+= w0*a2.w + w1*c2.w;
  }

  float e = expf(d + ACT_SHIFT);
  float alpha = 1.f - rsqrtf(1.f + e);
  if(!m) alpha = 0.f;
  alpha_w[i] = alpha;

  #pragma unroll
  for(int c = 0; c < 6; ++c)
    feat_bf[(size_t)i*6 + c] = packbf(f[2*c], f[2*c+1]);
}

// ---------------- per-ray compositing: one wave per ray, shfl prefix product ---
__global__ __launch_bounds__(256) void k_comp(const int* __restrict__ ray_id,
    float* __restrict__ alpha_w, float* __restrict__ out)
{
  int r = blockIdx.x*4 + (threadIdx.x >> 6);   // grid = NRAYS/4 blocks
  int lane = threadIdx.x & 63;
  int lo = 0, hi = M_SAMPLES;
  while(lo < hi){ int mid = (lo+hi) >> 1; if(ray_id[mid] < r) lo = mid+1; else hi = mid; }
  int s = lo;
  int lo2 = s, hi2 = M_SAMPLES;
  while(lo2 < hi2){ int mid = (lo2+hi2) >> 1; if(ray_id[mid] < r+1) lo2 = mid+1; else hi2 = mid; }
  int e = lo2;

  float carry = 1.f;
  for(int base = s; base < e; base += 64){
    int idx = base + lane;
    float a = (idx < e) ? alpha_w[idx] : 0.f;
    float incl = 1.f - a;
    #pragma unroll
    for(int d2 = 1; d2 < 64; d2 <<= 1){
      float t = __shfl_up(incl, d2);
      if(lane >= d2) incl *= t;
    }
    float excl = __shfl_up(incl, 1);
    if(lane == 0) excl = 1.f;
    if(idx < e) alpha_w[idx] = carry * excl * a;   // weight, in place
    carry *= __shfl(incl, 63);
  }
  if(lane == 0){ out[3*r+0] = carry; out[3*r+1] = carry; out[3*r+2] = carry; }
}

// ---------------- fused MLP -----------------------------------------------------
// 32x32x16 MFMA with A=weights, B=activations -> D[neuron][sample]:
// col=lane&31=sample, row=(reg&3)+8*(reg>>2)+4*(lane>>5)=neuron -> 2-contig b64 writes
template<int KDIM, int SROW, int DROW>
static __device__ inline void layer32(const unsigned short* src, unsigned short* dst,
    const unsigned short* __restrict__ wt, const float* __restrict__ bias,
    int wave, int ln, int kh)
{
  constexpr int NS = KDIM/16;
  int tile_s = wave & 1, tile_n = wave >> 1;
  const unsigned short* wbase = wt + (tile_n*32 + ln)*KDIM + kh*8;
  const unsigned short* abase = src + (tile_s*32 + ln)*SROW + kh*8;
  f32x16 acc = {0.f,0.f,0.f,0.f,0.f,0.f,0.f,0.f,0.f,0.f,0.f,0.f,0.f,0.f,0.f,0.f};
  #pragma unroll
  for(int st = 0; st < NS; ++st){
    bf16x8 af = *(const bf16x8*)(wbase + st*16);
    bf16x8 bfr = *(const bf16x8*)(abase + st*16);
    acc = __builtin_amdgcn_mfma_f32_32x32x16_bf16(af, bfr, acc, 0, 0, 0);
  }
  int scol = tile_s*32 + ln;
  #pragma unroll
  for(int g = 0; g < 4; ++g){
    int n0 = tile_n*32 + g*8 + kh*4;
    float4 bv = *(const float4*)(bias + n0);
    unsigned int lo = packbf(fmaxf(acc[4*g+0] + bv.x, 0.f), fmaxf(acc[4*g+1] + bv.y, 0.f));
    unsigned int hi = packbf(fmaxf(acc[4*g+2] + bv.z, 0.f), fmaxf(acc[4*g+3] + bv.w, 0.f));
    unsigned long long o = (unsigned long long)lo | ((unsigned long long)hi << 32);
    *(unsigned long long*)(dst + scol*DROW + n0) = o;
  }
}

__global__ __launch_bounds__(512) void k_mlp(const float* __restrict__ xyz,
    const int* __restrict__ ray_id, const unsigned int* __restrict__ feat_bf,
    const float* __restrict__ weights,
    const unsigned short* __restrict__ wt0, const unsigned short* __restrict__ wt1,
    const unsigned short* __restrict__ wt2, const unsigned short* __restrict__ wtr,
    const float* __restrict__ b0, const float* __restrict__ b1,
    const float* __restrict__ b2, const float* __restrict__ br,
    const float* __restrict__ ve, float* __restrict__ out)
{
  __shared__ alignas(16) unsigned short hA[64*ROWA];
  __shared__ alignas(16) unsigned short hB[64*ROWB];
  __shared__ float red[64*3];
  __shared__ float w_s[64];
  __shared__ int ray_s[64];

  int tid = threadIdx.x;
  int lane = tid & 63, wave = tid >> 6;
  int i = blockIdx.x*64 + lane;

  // phase 0: wave w<6 builds channels [16w,16w+16) of h0 for sample=lane
  //          (wave-uniform branches, conflict-free 2x ds_write_b128 per lane);
  //          waves 6,7 fill hB ve cols 128..159 + w_s/ray_s
  if(wave < 6){
    float x = xyz[3*i+0], y = xyz[3*i+1], z = xyz[3*i+2];
    unsigned int d[8];
    if(wave == 0){
      #pragma unroll
      for(int j = 0; j < 6; ++j) d[j] = feat_bf[(size_t)i*6 + j];
      d[6] = packbf(x, y);
      d[7] = packbf(z, __sinf(x));          // c15 = sin(x * 2^0)
    } else {
      float v[16];
      #pragma unroll
      for(int j = 0; j < 16; ++j){
        int c = wave*16 + j;
        float r;
        if(c >= 75) r = 0.f;
        else {
          int q = (c < 45) ? (c-15) : (c-45);
          int ci = q/10, p = q - ci*10;
          float xv = (ci == 0) ? x : ((ci == 1) ? y : z);
          float a = xv * (float)(1 << p);
          r = (c < 45) ? __sinf(a) : __cosf(a);
        }
        v[j] = r;
      }
      #pragma unroll
      for(int j = 0; j < 8; ++j) d[j] = packbf(v[2*j], v[2*j+1]);
    }
    uint4* p = (uint4*)(hA + lane*ROWA + wave*16);
    p[0] = make_uint4(d[0],d[1],d[2],d[3]);
    p[1] = make_uint4(d[4],d[5],d[6],d[7]);
  } else {
    int ray = ray_id[i];
    int base = 128 + (wave-6)*16;
    unsigned int d[8];
    #pragma unroll
    for(int j = 0; j < 8; ++j){
      int c0i = base - 128 + 2*j;
      float a = (c0i     < 27) ? ve[ray*27 + c0i]     : 0.f;
      float b = (c0i + 1 < 27) ? ve[ray*27 + c0i + 1] : 0.f;
      d[j] = packbf(a, b);
    }
    uint4* p = (uint4*)(hB + lane*ROWB + base);
    p[0] = make_uint4(d[0],d[1],d[2],d[3]);
    p[1] = make_uint4(d[4],d[5],d[6],d[7]);
    if(wave == 6){ w_s[lane] = weights[i]; ray_s[lane] = ray; }
  }
  __syncthreads();

  int ln = lane & 31, kh = lane >> 5;
  layer32< 96, ROWA, ROWB>(hA, hB, wt0, b0, wave, ln, kh);  __syncthreads();
  layer32<128, ROWB, ROWA>(hB, hA, wt1, b1, wave, ln, kh);  __syncthreads();
  layer32<128, ROWA, ROWB>(hA, hB, wt2, b2, wave, ln, kh);  __syncthreads();

  // rgb head via 16x16x32 MFMA, K=160 (128 h + 27 ve + 5 pad), waves 0..3 = m-tiles
  int col = lane & 15, q = lane >> 4;
  if(wave < 4){
    int mt = wave;
    f32x4 acc = {0.f, 0.f, 0.f, 0.f};
    const unsigned short* arow = hB + (mt*16 + col)*ROWB + q*8;
    const unsigned short* wrow = wtr + col*160 + q*8;
    #pragma unroll
    for(int ks = 0; ks < 5; ++ks){
      bf16x8 af = *(const bf16x8*)(arow + ks*32);
      bf16x8 bfr = *(const bf16x8*)(wrow + ks*32);
      acc = __builtin_amdgcn_mfma_f32_16x16x32_bf16(af, bfr, acc, 0, 0, 0);
    }
    if(col < 3){
      #pragma unroll
      for(int r = 0; r < 4; ++r){
        int sl = mt*16 + q*4 + r;
        float v = acc[r] + br[col];
        float sg = 1.f / (1.f + expf(-v));
        red[sl*3 + col] = w_s[sl] * sg;
      }
    }
  }
  __syncthreads();

  // segmented reduce over sorted ray ids, one atomic per segment
  if(tid < 192){
    int c = tid >> 6, ss = tid & 63;
    int sray = ray_s[ss];
    if(ss == 0 || ray_s[ss-1] != sray){
      float sum = 0.f;
      int j = ss;
      while(j < 64 && ray_s[j] == sray){ sum += red[j*3 + c]; ++j; }
      atomicAdd(&out[sray*3 + c], sum);
    }
  }
}

// ---------------- host ----------------------------------------------------------
extern "C" void kernel_launch(void* const* d_in, const int* in_sizes, int n_in,
                              void* d_out, int out_size, void* d_ws, size_t ws_size,
                              hipStream_t stream)
{
  const float* xyz      = (const float*)d_in[0];
  const int*   ray_id   = (const int*)  d_in[1];
  const float* viewdirs = (const float*)d_in[2];
  const void*  mask     =               d_in[3];
  const float* density  = (const float*)d_in[4];
  const float* k0       = (const float*)d_in[5];
  const float* W0 = (const float*)d_in[6];  const float* b0 = (const float*)d_in[7];
  const float* W1 = (const float*)d_in[8];  const float* b1 = (const float*)d_in[9];
  const float* W2 = (const float*)d_in[10]; const float* b2 = (const float*)d_in[11];
  const float* Wr = (const float*)d_in[12]; const float* br = (const float*)d_in[13];
  float* out = (float*)d_out;

  char* ws = (char*)d_ws;
  size_t off = 0;
  auto take = [&](size_t nbytes) -> void* {
    void* p = ws + off;
    off = (off + nbytes + 255) & ~(size_t)255;
    return p;
  };
  int*            flag    = (int*)           take(4);
  unsigned short* wt0     = (unsigned short*)take(128*96*2);
  unsigned short* wt1     = (unsigned short*)take(128*128*2);
  unsigned short* wt2     = (unsigned short*)take(128*128*2);
  unsigned short* wtr     = (unsigned short*)take(16*160*2);
  float*          ve      = (float*)         take((size_t)NRAYS*27*4);
  float*          alpha_w = (float*)         take((size_t)M_SAMPLES*4);
  unsigned int*   feat_bf = (unsigned int*)  take((size_t)M_SAMPLES*6*4);
  uint4*          packed  = (uint4*)         take((size_t)NVOX*32);
  bool use_packed = (ws_size >= off);

  k_detect <<<1,   64,  0, stream>>>((const unsigned int*)mask, flag);
  k_prep_w <<<186, 256, 0, stream>>>(W0, W1, W2, Wr, wt0, wt1, wt2, wtr);
  k_viewemb<<<864, 256, 0, stream>>>(viewdirs, ve);
  if(use_packed){
    k_repack       <<<(NVOX+255)/256, 256, 0, stream>>>(density, k0, packed);
    k_sample_packed<<<M_SAMPLES/256, 256, 0, stream>>>(xyz, mask, packed, flag,
                                                       alpha_w, feat_bf);
  } else {
    k_sample_direct<<<M_SAMPLES/256, 256, 0, stream>>>(xyz, mask, density, k0, flag,
                                                       alpha_w, feat_bf);
  }
  k_comp   <<<NRAYS/4, 256, 0, stream>>>(ray_id, alpha_w, out);
  k_mlp    <<<M_SAMPLES/64, 512, 0, stream>>>(xyz, ray_id, feat_bf, alpha_w,
                                              wt0, wt1, wt2, wtr, b0, b1, b2, br, ve, out);
}